// Round 1
// 2048.447 us; speedup vs baseline: 1.0064x; 1.0064x over previous
//
#include <hip/hip_runtime.h>
#include <hip/hip_bf16.h>

// Problem: B=8192, D=768, L=16384, K=100. ALL I/O fp32.
// out = [latents_pre_act (B*L) | latents (B*L) | recons (B*D)] fp32 concat.
//
//  k1: per-row mean/std, xn=(x-mu)/(std+eps)-pre_bias; write fp32 xn32 and
//      hi/lo bf16 split
//  k2: transpose W_enc [D,L] -> Wt32 [L,D] fp32 + Wh/Wl bf16 split
//  k3: MFMA GEMM, 3-term hi/lo product, NOW: 256x256 tile, 8 waves,
//      double-buffered LDS (128 KiB), stage-first + single raw s_barrier per
//      K-tile (T3-minimum pipeline), setprio around MFMA clusters, XCD-aware
//      block swizzle. Accumulation order identical to previous version.
//  k4: top-k with exact boundary resolution (bisection + f64 band re-derive),
//      scatter latents + fused sparse decode. Unchanged this round.

#define Bdim 8192
#define Ddim 768
#define Ldim 16384
#define Kdim 100
#define BAND_W 1.5e-4f
#define BAND_MAX 64

typedef short s16x8 __attribute__((ext_vector_type(8)));
typedef float f32x4 __attribute__((ext_vector_type(4)));

__device__ inline float key2float(unsigned int k) {
  unsigned int u = (k & 0x80000000u) ? (k & 0x7fffffffu) : ~k;
  return __uint_as_float(u);
}

// ---------------------------------------------------------------- normalize
__global__ __launch_bounds__(256) void normalize_kernel(
    const float* __restrict__ x, const float* __restrict__ pre_bias,
    __hip_bfloat16* __restrict__ xh, __hip_bfloat16* __restrict__ xl,
    float* __restrict__ xn32, float* __restrict__ mu_out, float* __restrict__ std_out) {
  const int r = blockIdx.x, t = threadIdx.x;
  const int lane = t & 63, wid = t >> 6;
  const float* xr = x + (size_t)r * Ddim;
  float v0 = xr[t], v1 = xr[t + 256], v2 = xr[t + 512];
  __shared__ float sred[4];
  float s = v0 + v1 + v2;
  for (int off = 32; off > 0; off >>= 1) s += __shfl_down(s, off, 64);
  if (lane == 0) sred[wid] = s;
  __syncthreads();
  float mu = (sred[0] + sred[1] + sred[2] + sred[3]) * (1.0f / 768.0f);
  __syncthreads();
  float d0 = v0 - mu, d1 = v1 - mu, d2 = v2 - mu;
  s = d0 * d0 + d1 * d1 + d2 * d2;
  for (int off = 32; off > 0; off >>= 1) s += __shfl_down(s, off, 64);
  if (lane == 0) sred[wid] = s;
  __syncthreads();
  float var = (sred[0] + sred[1] + sred[2] + sred[3]) * (1.0f / 768.0f);
  float sd = sqrtf(var);
  float inv = 1.0f / (sd + 1e-5f);
  size_t base = (size_t)r * Ddim;
  #pragma unroll
  for (int j = 0; j < 3; ++j) {
    int c = t + j * 256;
    float d = (j == 0 ? d0 : (j == 1 ? d1 : d2));
    float sn = d * inv - pre_bias[c];
    __hip_bfloat16 hi = __float2bfloat16(sn);
    float lo = sn - __bfloat162float(hi);
    xn32[base + c] = sn;
    xh[base + c] = hi;
    xl[base + c] = __float2bfloat16(lo);
  }
  if (t == 0) { mu_out[r] = mu; std_out[r] = sd; }
}

// ------------------------------------------------------- W transpose + split
__global__ __launch_bounds__(256) void wsplit_kernel(
    const float* __restrict__ W, __hip_bfloat16* __restrict__ Wh,
    __hip_bfloat16* __restrict__ Wl, float* __restrict__ Wt32) {
  __shared__ float tile[32][33];
  const int tx = threadIdx.x & 31, ty = threadIdx.x >> 5;
  const int l0 = blockIdx.x * 32, d0 = blockIdx.y * 32;
  #pragma unroll
  for (int i = ty; i < 32; i += 8)
    tile[i][tx] = W[(size_t)(d0 + i) * Ldim + l0 + tx];
  __syncthreads();
  #pragma unroll
  for (int i = ty; i < 32; i += 8) {
    float v = tile[tx][i];  // = W[d0+tx][l0+i]
    __hip_bfloat16 h = __float2bfloat16(v);
    float lo = v - __bfloat162float(h);
    const size_t off = (size_t)(l0 + i) * Ddim + d0 + tx;
    Wh[off] = h;
    Wl[off] = __float2bfloat16(lo);
    Wt32[off] = v;
  }
}

// ---------------------------------------------------------------- encode GEMM
// C[M=8192,N=16384] = (Ah+Al)[M,768] @ (Wh+Wl)^T ; W* is [N,768] k-contiguous.
// 3-term: ah*bh + al*bh + ah*bl  (al*bl dropped).
// 256x256 tile, BK=32(real), 512 thr / 8 waves (2Mx4N), per-wave 128x64 out.
// LDS 128 KiB: 2 dbuf x {Ah,Al,Bh,Bl}[256][32] bf16. Stage-first, 1 raw
// s_barrier per K-tile, vmcnt(0) only after the compute phase hid the loads.

#define GLL(gp, lp)                                                         \
  __builtin_amdgcn_global_load_lds(                                         \
      (const __attribute__((address_space(1))) void*)(gp),                  \
      (__attribute__((address_space(3))) void*)(lp), 16, 0, 0)

#define MFMA_BF16 __builtin_amdgcn_mfma_f32_16x16x32_bf16

// per K-tile: each wave moves 8 x 1KiB chunks (2 per array). Chunk c of an
// array covers rows [c*16, c*16+16) x 64B; HW writes dest base + lane*16B,
// lane l -> row c*16 + (l>>2), col bytes (l&3)*16  == source (l&3)*8 elems.
#define STAGE(kt, dAh, dAl, dBh, dBl) do {                                  \
    const size_t ko_ = (size_t)(kt) * 32;                                   \
    GLL(gA0 + ko_,             (dAh) + (wid * 2) * 512);                    \
    GLL(gA0 + ko_ + 16 * Ddim, (dAh) + (wid * 2 + 1) * 512);                \
    GLL(gA1 + ko_,             (dAl) + (wid * 2) * 512);                    \
    GLL(gA1 + ko_ + 16 * Ddim, (dAl) + (wid * 2 + 1) * 512);                \
    GLL(gB0 + ko_,             (dBh) + (wid * 2) * 512);                    \
    GLL(gB0 + ko_ + 16 * Ddim, (dBh) + (wid * 2 + 1) * 512);                \
    GLL(gB1 + ko_,             (dBl) + (wid * 2) * 512);                    \
    GLL(gB1 + ko_ + 16 * Ddim, (dBl) + (wid * 2 + 1) * 512);                \
  } while (0)

// 4 sub-phases of 2 m-frags x 4 n-frags x 3 terms = 24 MFMA each.
// Accumulation order per frag: hh, lh, hl (identical to previous version).
#define COMPUTE(dAh, dAl, dBh, dBl) do {                                    \
    s16x8 bh_[4], bl_[4];                                                   \
    _Pragma("unroll") for (int nt = 0; nt < 4; ++nt) {                      \
      const int rb_ = (wc * 64 + nt * 16 + lr) * 32 + koff;                 \
      bh_[nt] = *(const s16x8*)&(dBh)[rb_];                                 \
      bl_[nt] = *(const s16x8*)&(dBl)[rb_];                                 \
    }                                                                       \
    _Pragma("unroll") for (int ph = 0; ph < 4; ++ph) {                      \
      const int r0_ = (wr * 128 + ph * 32 + lr) * 32 + koff;                \
      const int r1_ = r0_ + 16 * 32;                                        \
      s16x8 a0h_ = *(const s16x8*)&(dAh)[r0_];                              \
      s16x8 a0l_ = *(const s16x8*)&(dAl)[r0_];                              \
      s16x8 a1h_ = *(const s16x8*)&(dAh)[r1_];                              \
      s16x8 a1l_ = *(const s16x8*)&(dAl)[r1_];                              \
      __builtin_amdgcn_s_setprio(1);                                        \
      _Pragma("unroll") for (int nt = 0; nt < 4; ++nt) {                    \
        acc[2*ph][nt]   = MFMA_BF16(a0h_, bh_[nt], acc[2*ph][nt], 0, 0, 0); \
        acc[2*ph][nt]   = MFMA_BF16(a0l_, bh_[nt], acc[2*ph][nt], 0, 0, 0); \
        acc[2*ph][nt]   = MFMA_BF16(a0h_, bl_[nt], acc[2*ph][nt], 0, 0, 0); \
        acc[2*ph+1][nt] = MFMA_BF16(a1h_, bh_[nt], acc[2*ph+1][nt], 0, 0, 0);\
        acc[2*ph+1][nt] = MFMA_BF16(a1l_, bh_[nt], acc[2*ph+1][nt], 0, 0, 0);\
        acc[2*ph+1][nt] = MFMA_BF16(a1h_, bl_[nt], acc[2*ph+1][nt], 0, 0, 0);\
      }                                                                     \
      __builtin_amdgcn_s_setprio(0);                                        \
    }                                                                       \
  } while (0)

__global__ __launch_bounds__(512, 2) void encode_gemm_kernel(
    const __hip_bfloat16* __restrict__ xh, const __hip_bfloat16* __restrict__ xl,
    const __hip_bfloat16* __restrict__ wh, const __hip_bfloat16* __restrict__ wl,
    const float* __restrict__ lb, float* __restrict__ out0) {
  __shared__ __align__(16) __hip_bfloat16 sAh0[8192];
  __shared__ __align__(16) __hip_bfloat16 sAl0[8192];
  __shared__ __align__(16) __hip_bfloat16 sBh0[8192];
  __shared__ __align__(16) __hip_bfloat16 sBl0[8192];
  __shared__ __align__(16) __hip_bfloat16 sAh1[8192];
  __shared__ __align__(16) __hip_bfloat16 sAl1[8192];
  __shared__ __align__(16) __hip_bfloat16 sBh1[8192];
  __shared__ __align__(16) __hip_bfloat16 sBl1[8192];

  const int t = threadIdx.x;
  const int wid = t >> 6, lane = t & 63;
  const int lr = lane & 15, quad = lane >> 4;
  const int koff = quad * 8;
  const int wr = wid >> 2, wc = wid & 3;  // wave grid: 2 (M) x 4 (N)

  // XCD-aware swizzle: 2048 blocks, 8 XCDs, 256 consecutive work items per
  // XCD; within a chunk bx varies fast -> A row-panel stays hot in XCD L2.
  const int flat = blockIdx.y * 64 + blockIdx.x;
  const int swz = (flat & 7) * 256 + (flat >> 3);
  const int m0 = (swz >> 6) * 256;
  const int n0 = (swz & 63) * 256;

  const int srow = lane >> 2, scol = (lane & 3) * 8;
  const __hip_bfloat16* gA0 = xh + (size_t)(m0 + wid * 32 + srow) * Ddim + scol;
  const __hip_bfloat16* gA1 = xl + (size_t)(m0 + wid * 32 + srow) * Ddim + scol;
  const __hip_bfloat16* gB0 = wh + (size_t)(n0 + wid * 32 + srow) * Ddim + scol;
  const __hip_bfloat16* gB1 = wl + (size_t)(n0 + wid * 32 + srow) * Ddim + scol;

  f32x4 acc[8][4];
  #pragma unroll
  for (int i = 0; i < 8; ++i)
    #pragma unroll
    for (int j = 0; j < 4; ++j) acc[i][j] = (f32x4){0.f, 0.f, 0.f, 0.f};

  STAGE(0, sAh0, sAl0, sBh0, sBl0);
  asm volatile("s_waitcnt vmcnt(0)" ::: "memory");
  __builtin_amdgcn_s_barrier();

  #pragma unroll 1
  for (int kt = 0; kt < Ddim / 32; kt += 2) {
    // stage tile kt+1 into buf1 (its last readers synced at prev barrier)
    STAGE(kt + 1, sAh1, sAl1, sBh1, sBl1);
    COMPUTE(sAh0, sAl0, sBh0, sBl0);
    asm volatile("s_waitcnt vmcnt(0)" ::: "memory");  // kt+1 loads landed
    __builtin_amdgcn_s_barrier();
    if (kt + 2 < Ddim / 32) STAGE(kt + 2, sAh0, sAl0, sBh0, sBl0);
    COMPUTE(sAh1, sAl1, sBh1, sBl1);
    asm volatile("s_waitcnt vmcnt(0)" ::: "memory");
    __builtin_amdgcn_s_barrier();
  }

  #pragma unroll
  for (int nt = 0; nt < 4; ++nt) {
    const int n = n0 + wc * 64 + nt * 16 + lr;
    const float bias = lb[n];
    #pragma unroll
    for (int mt = 0; mt < 8; ++mt) {
      const int mb = m0 + wr * 128 + mt * 16 + quad * 4;
      #pragma unroll
      for (int rg = 0; rg < 4; ++rg)
        out0[(size_t)(mb + rg) * Ldim + n] = acc[mt][nt][rg] + bias;
    }
  }
}

// ---------------------------------------------------------------- topk+decode
__global__ __launch_bounds__(256) void topk_decode_kernel(
    const float* __restrict__ pre, const float* __restrict__ xn32,
    const float* __restrict__ Wt32, const float* __restrict__ lb,
    const float* __restrict__ Wdec, const float* __restrict__ pre_bias,
    const float* __restrict__ mu_arr, const float* __restrict__ std_arr,
    float* __restrict__ out_lat, float* __restrict__ out_rec) {
  const int r = blockIdx.x, t = threadIdx.x;
  const int lane = t & 63, wid = t >> 6;
  const float* row = pre + (size_t)r * Ldim;

  unsigned int keys[64];
  #pragma unroll
  for (int j = 0; j < 64; ++j) {
    unsigned int u = __float_as_uint(row[t + j * 256]);
    keys[j] = (u & 0x80000000u) ? ~u : (u | 0x80000000u);
  }

  __shared__ int sred[4];
  __shared__ int s_gt, s_band;
  __shared__ int sel_idx[128];
  __shared__ float sel_val[128];
  __shared__ int band_idx[BAND_MAX];
  __shared__ double band_rv[BAND_MAX];   // f64 dot + bias (rank key)
  __shared__ float band_ov[BAND_MAX];    // fp32 output value
  __shared__ float sxn[Ddim];

  // 32-step bisection: kth = K-th largest key (exact on approx values)
  unsigned int kth = 0u;
  for (int bit = 31; bit >= 0; --bit) {
    const unsigned int cand = kth | (1u << bit);
    int c = 0;
    #pragma unroll
    for (int j = 0; j < 64; ++j) c += (keys[j] >= cand) ? 1 : 0;
    for (int off = 32; off > 0; off >>= 1) c += __shfl_down(c, off, 64);
    if (lane == 0) sred[wid] = c;
    __syncthreads();
    const int tot = sred[0] + sred[1] + sred[2] + sred[3];
    __syncthreads();
    if (tot >= Kdim) kth = cand;
  }

  const float kv = key2float(kth);
  const float Thi = kv + BAND_W, Tlo = kv - BAND_W;

  if (t == 0) { s_gt = 0; s_band = 0; }
  // stage xn row while we're at it
  sxn[t] = xn32[(size_t)r * Ddim + t];
  sxn[t + 256] = xn32[(size_t)r * Ddim + t + 256];
  sxn[t + 512] = xn32[(size_t)r * Ddim + t + 512];
  __syncthreads();

  #pragma unroll
  for (int j = 0; j < 64; ++j) {
    const float v = key2float(keys[j]);
    if (v > Thi) {
      const int p = atomicAdd(&s_gt, 1);
      sel_idx[p] = t + j * 256;
      sel_val[p] = v;
    } else if (v >= Tlo) {
      const int p = atomicAdd(&s_band, 1);
      if (p < BAND_MAX) band_idx[p] = t + j * 256;
    }
  }
  __syncthreads();

  const int A = s_gt;                       // certainly in top-K (<= 99)
  const int m = min(s_band, BAND_MAX);      // uncertain band (expected ~1-2)
  const int need = Kdim - A;                // 1..m slots to fill from band

  // exact f64 re-derivation of band members (one wave per candidate)
  for (int c = wid; c < m; c += 4) {
    const int ci = band_idx[c];
    const float* wr = Wt32 + (size_t)ci * Ddim;
    double s = 0.0;
    #pragma unroll
    for (int j = 0; j < 12; ++j) {
      const int e = lane + j * 64;
      s += (double)sxn[e] * (double)wr[e];
    }
    for (int off = 32; off > 0; off >>= 1) s += __shfl_down(s, off, 64);
    if (lane == 0) {
      band_rv[c] = s + (double)lb[ci];
      band_ov[c] = (float)s + lb[ci];   // np op order: fp32(dot) + bias
    }
  }
  __syncthreads();

  // rank band members (desc value, ties -> lower index); top `need` join sel
  if (t < m) {
    const double mine = band_rv[t];
    const int myi = band_idx[t];
    int rank = 0;
    for (int j = 0; j < m; ++j) {
      if (band_rv[j] > mine || (band_rv[j] == mine && band_idx[j] < myi)) ++rank;
    }
    if (rank < need) {
      const int p = atomicAdd(&s_gt, 1);
      sel_idx[p] = myi;
      sel_val[p] = band_ov[t];
    }
  }
  __syncthreads();
  // now sel_* holds exactly Kdim entries

  // output 1: zero the row, scatter the kept values
  float* lat = out_lat + (size_t)r * Ldim;
  float4 z; z.x = 0.f; z.y = 0.f; z.z = 0.f; z.w = 0.f;
  float4* lp = (float4*)lat;
  #pragma unroll
  for (int j = 0; j < 16; ++j) lp[t + j * 256] = z;
  __syncthreads();
  if (t < Kdim) lat[sel_idx[t]] = sel_val[t];

  // output 2: sparse decode + denormalize
  float a0 = 0.f, a1 = 0.f, a2 = 0.f;
  for (int j = 0; j < Kdim; ++j) {
    const float v = sel_val[j];
    const float* wr = Wdec + (size_t)sel_idx[j] * Ddim;
    a0 += v * wr[t];
    a1 += v * wr[t + 256];
    a2 += v * wr[t + 512];
  }
  const float sd = std_arr[r], mv = mu_arr[r];
  float* rec = out_rec + (size_t)r * Ddim;
  rec[t]       = (a0 + pre_bias[t]) * sd + mv;
  rec[t + 256] = (a1 + pre_bias[t + 256]) * sd + mv;
  rec[t + 512] = (a2 + pre_bias[t + 512]) * sd + mv;
}

// ---------------------------------------------------------------- launch
extern "C" void kernel_launch(void* const* d_in, const int* in_sizes, int n_in,
                              void* d_out, int out_size, void* d_ws, size_t ws_size,
                              hipStream_t stream) {
  const float* x     = (const float*)d_in[0];
  const float* pre_b = (const float*)d_in[1];
  const float* lat_b = (const float*)d_in[2];
  const float* W_enc = (const float*)d_in[3];
  const float* W_dec = (const float*)d_in[4];

  float* out0 = (float*)d_out;                 // latents_pre_act [B,L]
  float* out1 = out0 + (size_t)Bdim * Ldim;    // latents         [B,L]
  float* out2 = out1 + (size_t)Bdim * Ldim;    // recons          [B,D]

  char* p = (char*)d_ws;
  __hip_bfloat16* xh = (__hip_bfloat16*)p; p += (size_t)Bdim * Ddim * 2;
  __hip_bfloat16* xl = (__hip_bfloat16*)p; p += (size_t)Bdim * Ddim * 2;
  __hip_bfloat16* Wh = (__hip_bfloat16*)p; p += (size_t)Ldim * Ddim * 2;
  __hip_bfloat16* Wl = (__hip_bfloat16*)p; p += (size_t)Ldim * Ddim * 2;
  float* xn32 = (float*)p;                 p += (size_t)Bdim * Ddim * 4;
  float* Wt32 = (float*)p;                 p += (size_t)Ldim * Ddim * 4;
  float* muv  = (float*)p;                 p += (size_t)Bdim * 4;
  float* sdv  = (float*)p;

  normalize_kernel<<<Bdim, 256, 0, stream>>>(x, pre_b, xh, xl, xn32, muv, sdv);
  wsplit_kernel<<<dim3(Ldim / 32, Ddim / 32), 256, 0, stream>>>(W_enc, Wh, Wl, Wt32);
  encode_gemm_kernel<<<dim3(Ldim / 256, Bdim / 256), 512, 0, stream>>>(
      xh, xl, Wh, Wl, lat_b, out0);
  topk_decode_kernel<<<Bdim, 256, 0, stream>>>(
      out0, xn32, Wt32, lat_b, W_dec, pre_b, muv, sdv, out1, out2);
}

// Round 3
// 2017.406 us; speedup vs baseline: 1.0219x; 1.0154x over previous
//
#include <hip/hip_runtime.h>
#include <hip/hip_bf16.h>

// Problem: B=8192, D=768, L=16384, K=100. ALL I/O fp32.
// out = [latents_pre_act (B*L) | latents (B*L) | recons (B*D)] fp32 concat.
//
//  k1: per-row mean/std, xn=(x-mu)/(std+eps)-pre_bias; fp32 xn32 + hi/lo bf16
//  k2: transpose W_enc [D,L] -> Wt32 [L,D] fp32 + Wh/Wl bf16 split
//  k3: MFMA GEMM, 3-term hi/lo, 256x256 tile, 8 waves, dbuf LDS 128 KiB,
//      4-phase K-tiles with COUNTED vmcnt (3,4,5,6) — loads for tile t+1 are
//      issued 2/phase during tile t and never drained to 0 in the main loop.
//      Raw s_barrier + asm fences both sides (no __syncthreads -> no vmcnt(0)
//      drain). MFMA order identical to prior rounds (bit-identical numerics).
//  k4: top-k: 10-bit coarse bisection -> compaction (<=768 cands incl. band
//      margin 2^12 key-steps >= 4.9e-4 > BAND_W) -> wave0 finishes 22 bits on
//      regs -> exact band resolution (f64) -> scatter + fused sparse decode.

#define Bdim 8192
#define Ddim 768
#define Ldim 16384
#define Kdim 100
#define BAND_W 1.5e-4f
#define BAND_MAX 64
#define CAP 768

typedef short s16x8 __attribute__((ext_vector_type(8)));
typedef float f32x4 __attribute__((ext_vector_type(4)));

__device__ inline float key2float(unsigned int k) {
  unsigned int u = (k & 0x80000000u) ? (k & 0x7fffffffu) : ~k;
  return __uint_as_float(u);
}

// ---------------------------------------------------------------- normalize
__global__ __launch_bounds__(256) void normalize_kernel(
    const float* __restrict__ x, const float* __restrict__ pre_bias,
    __hip_bfloat16* __restrict__ xh, __hip_bfloat16* __restrict__ xl,
    float* __restrict__ xn32, float* __restrict__ mu_out, float* __restrict__ std_out) {
  const int r = blockIdx.x, t = threadIdx.x;
  const int lane = t & 63, wid = t >> 6;
  const float* xr = x + (size_t)r * Ddim;
  float v0 = xr[t], v1 = xr[t + 256], v2 = xr[t + 512];
  __shared__ float sred[4];
  float s = v0 + v1 + v2;
  for (int off = 32; off > 0; off >>= 1) s += __shfl_down(s, off, 64);
  if (lane == 0) sred[wid] = s;
  __syncthreads();
  float mu = (sred[0] + sred[1] + sred[2] + sred[3]) * (1.0f / 768.0f);
  __syncthreads();
  float d0 = v0 - mu, d1 = v1 - mu, d2 = v2 - mu;
  s = d0 * d0 + d1 * d1 + d2 * d2;
  for (int off = 32; off > 0; off >>= 1) s += __shfl_down(s, off, 64);
  if (lane == 0) sred[wid] = s;
  __syncthreads();
  float var = (sred[0] + sred[1] + sred[2] + sred[3]) * (1.0f / 768.0f);
  float sd = sqrtf(var);
  float inv = 1.0f / (sd + 1e-5f);
  size_t base = (size_t)r * Ddim;
  #pragma unroll
  for (int j = 0; j < 3; ++j) {
    int c = t + j * 256;
    float d = (j == 0 ? d0 : (j == 1 ? d1 : d2));
    float sn = d * inv - pre_bias[c];
    __hip_bfloat16 hi = __float2bfloat16(sn);
    float lo = sn - __bfloat162float(hi);
    xn32[base + c] = sn;
    xh[base + c] = hi;
    xl[base + c] = __float2bfloat16(lo);
  }
  if (t == 0) { mu_out[r] = mu; std_out[r] = sd; }
}

// ------------------------------------------------------- W transpose + split
__global__ __launch_bounds__(256) void wsplit_kernel(
    const float* __restrict__ W, __hip_bfloat16* __restrict__ Wh,
    __hip_bfloat16* __restrict__ Wl, float* __restrict__ Wt32) {
  __shared__ float tile[32][33];
  const int tx = threadIdx.x & 31, ty = threadIdx.x >> 5;
  const int l0 = blockIdx.x * 32, d0 = blockIdx.y * 32;
  #pragma unroll
  for (int i = ty; i < 32; i += 8)
    tile[i][tx] = W[(size_t)(d0 + i) * Ldim + l0 + tx];
  __syncthreads();
  #pragma unroll
  for (int i = ty; i < 32; i += 8) {
    float v = tile[tx][i];  // = W[d0+tx][l0+i]
    __hip_bfloat16 h = __float2bfloat16(v);
    float lo = v - __bfloat162float(h);
    const size_t off = (size_t)(l0 + i) * Ddim + d0 + tx;
    Wh[off] = h;
    Wl[off] = __float2bfloat16(lo);
    Wt32[off] = v;
  }
}

// ---------------------------------------------------------------- encode GEMM
#define GLL(gp, lp)                                                         \
  __builtin_amdgcn_global_load_lds(                                         \
      (const __attribute__((address_space(1))) void*)(gp),                  \
      (__attribute__((address_space(3))) void*)(lp), 16, 0, 0)

#define MFMA_BF16 __builtin_amdgcn_mfma_f32_16x16x32_bf16

#define VMW_(n) asm volatile("s_waitcnt vmcnt(" #n ")" ::: "memory")
#define VMW(n) VMW_(n)
#define BARRIER do { asm volatile("" ::: "memory");                         \
                     __builtin_amdgcn_s_barrier();                          \
                     asm volatile("" ::: "memory"); } while (0)

// per-wave issue pairs (for tile at k-offset kk, into buffer b):
#define ISSUE_B0(b, kk) do {                                                \
    GLL(pB0a + (kk), smem + (b) * 32768 + oB0a);                            \
    GLL(pB0b + (kk), smem + (b) * 32768 + oB0b); } while (0)
#define ISSUE_B1(b, kk) do {                                                \
    GLL(pB1a + (kk), smem + (b) * 32768 + oB1a);                            \
    GLL(pB1b + (kk), smem + (b) * 32768 + oB1b); } while (0)
#define ISSUE_A01(b, kk) do {                                               \
    GLL(pA0 + (kk), smem + (b) * 32768 + oA0);                              \
    GLL(pA1 + (kk), smem + (b) * 32768 + oA1); } while (0)
#define ISSUE_A23(b, kk) do {                                               \
    GLL(pA2 + (kk), smem + (b) * 32768 + oA2);                              \
    GLL(pA3 + (kk), smem + (b) * 32768 + oA3); } while (0)

// B fragments for this tile (persist across the 4 phases)
#define LOADB(b) do {                                                       \
    _Pragma("unroll") for (int nt = 0; nt < 4; ++nt) {                      \
      const int rb_ = (b) * 32768 + 16384 + (wc * 64 + nt * 16 + lr) * 32 + koff; \
      bh_[nt] = *(const s16x8*)&smem[rb_];                                  \
      bl_[nt] = *(const s16x8*)&smem[rb_ + 8192];                           \
    } } while (0)

// phase p: A-quadrant p, 24 MFMA; order hh,lh,hl identical to prior rounds
#define PHASE_MFMA(b, p) do {                                               \
    const int r0_ = (b) * 32768 + (wr * 128 + (p) * 32 + lr) * 32 + koff;   \
    s16x8 a0h_ = *(const s16x8*)&smem[r0_];                                 \
    s16x8 a0l_ = *(const s16x8*)&smem[r0_ + 8192];                          \
    s16x8 a1h_ = *(const s16x8*)&smem[r0_ + 16 * 32];                       \
    s16x8 a1l_ = *(const s16x8*)&smem[r0_ + 8192 + 16 * 32];                \
    __builtin_amdgcn_s_setprio(1);                                          \
    _Pragma("unroll") for (int nt = 0; nt < 4; ++nt) {                      \
      acc[2*(p)][nt]   = MFMA_BF16(a0h_, bh_[nt], acc[2*(p)][nt], 0, 0, 0); \
      acc[2*(p)][nt]   = MFMA_BF16(a0l_, bh_[nt], acc[2*(p)][nt], 0, 0, 0); \
      acc[2*(p)][nt]   = MFMA_BF16(a0h_, bl_[nt], acc[2*(p)][nt], 0, 0, 0); \
      acc[2*(p)+1][nt] = MFMA_BF16(a1h_, bh_[nt], acc[2*(p)+1][nt], 0, 0, 0);\
      acc[2*(p)+1][nt] = MFMA_BF16(a1l_, bh_[nt], acc[2*(p)+1][nt], 0, 0, 0);\
      acc[2*(p)+1][nt] = MFMA_BF16(a1h_, bl_[nt], acc[2*(p)+1][nt], 0, 0, 0);\
    }                                                                       \
    __builtin_amdgcn_s_setprio(0);                                          \
  } while (0)

// one K-tile (buffer b), staging tile at knext into buffer 1-b when HAS_NEXT.
// entry waits V0..V3: steady 3,4,5,6 (never 0); last tile 3,2,1,0.
#define TILE(b, knext, HAS_NEXT, V0, V1, V2, V3) do {                       \
    s16x8 bh_[4], bl_[4];                                                   \
    VMW(V0); BARRIER;                                                       \
    LOADB(b);                                                               \
    if (HAS_NEXT) ISSUE_B0(1 - (b), knext);                                 \
    PHASE_MFMA(b, 0);                                                       \
    VMW(V1); BARRIER;                                                       \
    if (HAS_NEXT) ISSUE_B1(1 - (b), knext);                                 \
    PHASE_MFMA(b, 1);                                                       \
    VMW(V2); BARRIER;                                                       \
    if (HAS_NEXT) ISSUE_A01(1 - (b), knext);                                \
    PHASE_MFMA(b, 2);                                                       \
    VMW(V3); BARRIER;                                                       \
    if (HAS_NEXT) ISSUE_A23(1 - (b), knext);                                \
    PHASE_MFMA(b, 3);                                                       \
  } while (0)

__global__ __launch_bounds__(512, 2) void encode_gemm_kernel(
    const __hip_bfloat16* __restrict__ xh, const __hip_bfloat16* __restrict__ xl,
    const __hip_bfloat16* __restrict__ wh, const __hip_bfloat16* __restrict__ wl,
    const float* __restrict__ lb, float* __restrict__ out0) {
  // 128 KiB: buf b at b*32768 elems; Ah@+0, Al@+8192, Bh@+16384, Bl@+24576
  __shared__ __align__(16) __hip_bfloat16 smem[65536];

  const int t = threadIdx.x;
  const int wid = t >> 6, lane = t & 63;
  const int lr = lane & 15, quad = lane >> 4;
  const int koff = quad * 8;
  const int wr = wid >> 2, wc = wid & 3;  // wave grid: 2 (M) x 4 (N)

  const int flat = blockIdx.y * 64 + blockIdx.x;
  const int swz = (flat & 7) * 256 + (flat >> 3);
  const int m0 = (swz >> 6) * 256;
  const int n0 = (swz & 63) * 256;

  const int srow = lane >> 2, scol = (lane & 3) * 8;

  // staging ownership: B chunks 2w,2w+1 of Bh and Bl; A chunks re-mapped so
  // the chunk needed at phase p is every wave's p-th A issue:
  //   warc = wid&3, aoff = (warc>>1)*8 + (warc&1); group g -> chunk aoff+2g
  //   waves 0-3 stage Ah, waves 4-7 stage Al.
  const int cb0 = wid * 2, cb1 = wid * 2 + 1;
  const int warc = wid & 3;
  const int aoff = (warc >> 1) * 8 + (warc & 1);
  const __hip_bfloat16* aSrc = (wid < 4) ? xh : xl;
  const int aLds = (wid < 4) ? 0 : 8192;

  const __hip_bfloat16* pB0a = wh + (size_t)(n0 + cb0 * 16 + srow) * Ddim + scol;
  const __hip_bfloat16* pB0b = wh + (size_t)(n0 + cb1 * 16 + srow) * Ddim + scol;
  const __hip_bfloat16* pB1a = wl + (size_t)(n0 + cb0 * 16 + srow) * Ddim + scol;
  const __hip_bfloat16* pB1b = wl + (size_t)(n0 + cb1 * 16 + srow) * Ddim + scol;
  const __hip_bfloat16* pA0 = aSrc + (size_t)(m0 + (aoff + 0) * 16 + srow) * Ddim + scol;
  const __hip_bfloat16* pA1 = aSrc + (size_t)(m0 + (aoff + 2) * 16 + srow) * Ddim + scol;
  const __hip_bfloat16* pA2 = aSrc + (size_t)(m0 + (aoff + 4) * 16 + srow) * Ddim + scol;
  const __hip_bfloat16* pA3 = aSrc + (size_t)(m0 + (aoff + 6) * 16 + srow) * Ddim + scol;
  const int oB0a = 16384 + cb0 * 512, oB0b = 16384 + cb1 * 512;
  const int oB1a = 24576 + cb0 * 512, oB1b = 24576 + cb1 * 512;
  const int oA0 = aLds + (aoff + 0) * 512, oA1 = aLds + (aoff + 2) * 512;
  const int oA2 = aLds + (aoff + 4) * 512, oA3 = aLds + (aoff + 6) * 512;

  f32x4 acc[8][4];
  #pragma unroll
  for (int i = 0; i < 8; ++i)
    #pragma unroll
    for (int j = 0; j < 4; ++j) acc[i][j] = (f32x4){0.f, 0.f, 0.f, 0.f};

  // prologue: tile 0 -> buf 0, same per-wave issue order as steady state
  ISSUE_B0(0, 0); ISSUE_B1(0, 0); ISSUE_A01(0, 0); ISSUE_A23(0, 0);

  #pragma unroll 1
  for (int kt = 0; kt < 22; kt += 2) {
    TILE(0, (kt + 1) * 32, true, 3, 4, 5, 6);
    TILE(1, (kt + 2) * 32, true, 3, 4, 5, 6);
  }
  TILE(0, 23 * 32, true, 3, 4, 5, 6);   // tile 22, stages tile 23
  TILE(1, 0, false, 3, 2, 1, 0);        // tile 23, drain

  #pragma unroll
  for (int nt = 0; nt < 4; ++nt) {
    const int n = n0 + wc * 64 + nt * 16 + lr;
    const float bias = lb[n];
    #pragma unroll
    for (int mt = 0; mt < 8; ++mt) {
      const int mb = m0 + wr * 128 + mt * 16 + quad * 4;
      #pragma unroll
      for (int rg = 0; rg < 4; ++rg)
        out0[(size_t)(mb + rg) * Ldim + n] = acc[mt][nt][rg] + bias;
    }
  }
}

// ---------------------------------------------------------------- topk+decode
__global__ __launch_bounds__(256) void topk_decode_kernel(
    const float* __restrict__ pre, const float* __restrict__ xn32,
    const float* __restrict__ Wt32, const float* __restrict__ lb,
    const float* __restrict__ Wdec, const float* __restrict__ pre_bias,
    const float* __restrict__ mu_arr, const float* __restrict__ std_arr,
    float* __restrict__ out_lat, float* __restrict__ out_rec) {
  const int r = blockIdx.x, t = threadIdx.x;
  const int lane = t & 63, wid = t >> 6;
  const float* row = pre + (size_t)r * Ldim;

  unsigned int keys[64];
  #pragma unroll
  for (int j = 0; j < 64; ++j) {
    unsigned int u = __float_as_uint(row[t + j * 256]);
    keys[j] = (u & 0x80000000u) ? ~u : (u | 0x80000000u);
  }

  __shared__ int sred[4];
  __shared__ unsigned int s_kth;
  __shared__ int s_cnt, s_gt, s_band;
  __shared__ unsigned int ckey[CAP];
  __shared__ int cidx[CAP];
  __shared__ int sel_idx[128];
  __shared__ float sel_val[128];
  __shared__ int band_idx[BAND_MAX];
  __shared__ double band_rv[BAND_MAX];
  __shared__ float band_ov[BAND_MAX];
  __shared__ float sxn[Ddim];

  // coarse bisection: bits 31..22 only (10 reg-scans instead of 32)
  unsigned int kth = 0u;
  int curcnt = Ldim;
  for (int bit = 31; bit >= 22; --bit) {
    const unsigned int cand = kth | (1u << bit);
    int c = 0;
    #pragma unroll
    for (int j = 0; j < 64; ++j) c += (keys[j] >= cand) ? 1 : 0;
    for (int off = 32; off > 0; off >>= 1) c += __shfl_down(c, off, 64);
    if (lane == 0) sred[wid] = c;
    __syncthreads();
    const int tot = sred[0] + sred[1] + sred[2] + sred[3];
    __syncthreads();
    if (tot >= Kdim) { kth = cand; curcnt = tot; }
  }
  // safety: if the prefix count could overflow the compaction cap, keep
  // bisecting (never taken for N(0,1)-like rows where count(>=2.0) ~ 375)
  for (int bit = 21; bit >= 13 && curcnt > CAP - 64; --bit) {
    const unsigned int cand = kth | (1u << bit);
    int c = 0;
    #pragma unroll
    for (int j = 0; j < 64; ++j) c += (keys[j] >= cand) ? 1 : 0;
    for (int off = 32; off > 0; off >>= 1) c += __shfl_down(c, off, 64);
    if (lane == 0) sred[wid] = c;
    __syncthreads();
    const int tot = sred[0] + sred[1] + sred[2] + sred[3];
    __syncthreads();
    if (tot >= Kdim) { kth = cand; curcnt = tot; }
  }

  if (t == 0) { s_cnt = 0; s_gt = 0; s_band = 0; }
  sxn[t] = xn32[(size_t)r * Ddim + t];
  sxn[t + 256] = xn32[(size_t)r * Ddim + t + 256];
  sxn[t + 512] = xn32[(size_t)r * Ddim + t + 512];
  __syncthreads();

  // compact all keys >= prefix - 2^12 (margin >= 4096 key-steps, i.e. >=
  // ~4.9e-4 in value near 2.0 — covers the BAND_W=1.5e-4 band below kv)
  const unsigned int Tc = kth - (1u << 12);
  #pragma unroll
  for (int j = 0; j < 64; ++j) {
    if (keys[j] >= Tc) {
      const int p = atomicAdd(&s_cnt, 1);
      if (p < CAP) { ckey[p] = keys[j]; cidx[p] = t + j * 256; }
    }
  }
  __syncthreads();
  const int cnt = min(s_cnt, CAP);

  // wave 0 finishes the bisection (bits 21..0, idempotent) on registers
  if (wid == 0) {
    unsigned int rk[12];
    #pragma unroll
    for (int e = 0; e < 12; ++e) {
      const int ii = lane + e * 64;
      rk[e] = (ii < cnt) ? ckey[ii] : 0u;
    }
    unsigned int kk = kth;
    for (int bit = 21; bit >= 0; --bit) {
      const unsigned int cand = kk | (1u << bit);
      int c = 0;
      #pragma unroll
      for (int e = 0; e < 12; ++e) c += (rk[e] >= cand) ? 1 : 0;
      for (int off = 32; off > 0; off >>= 1) c += __shfl_down(c, off, 64);
      c = __shfl(c, 0, 64);
      if (c >= Kdim) kk = cand;
    }
    if (lane == 0) s_kth = kk;
  }
  __syncthreads();

  const float kv = key2float(s_kth);
  const float Thi = kv + BAND_W, Tlo = kv - BAND_W;

  // classification over the compacted list
  #pragma unroll
  for (int e = 0; e < 3; ++e) {
    const int ii = t + e * 256;
    if (ii < cnt) {
      const float v = key2float(ckey[ii]);
      if (v > Thi) {
        const int p = atomicAdd(&s_gt, 1);
        sel_idx[p] = cidx[ii];
        sel_val[p] = v;
      } else if (v >= Tlo) {
        const int p = atomicAdd(&s_band, 1);
        if (p < BAND_MAX) band_idx[p] = cidx[ii];
      }
    }
  }
  __syncthreads();

  const int A = s_gt;                       // certainly in top-K (<= 99)
  const int m = min(s_band, BAND_MAX);      // uncertain band (expected ~1-2)
  const int need = Kdim - A;                // 1..m slots to fill from band

  // exact f64 re-derivation of band members (one wave per candidate)
  for (int c = wid; c < m; c += 4) {
    const int ci = band_idx[c];
    const float* wr = Wt32 + (size_t)ci * Ddim;
    double s = 0.0;
    #pragma unroll
    for (int j = 0; j < 12; ++j) {
      const int e = lane + j * 64;
      s += (double)sxn[e] * (double)wr[e];
    }
    for (int off = 32; off > 0; off >>= 1) s += __shfl_down(s, off, 64);
    if (lane == 0) {
      band_rv[c] = s + (double)lb[ci];
      band_ov[c] = (float)s + lb[ci];   // np op order: fp32(dot) + bias
    }
  }
  __syncthreads();

  // rank band members (desc value, ties -> lower index); top `need` join sel
  if (t < m) {
    const double mine = band_rv[t];
    const int myi = band_idx[t];
    int rank = 0;
    for (int j = 0; j < m; ++j) {
      if (band_rv[j] > mine || (band_rv[j] == mine && band_idx[j] < myi)) ++rank;
    }
    if (rank < need) {
      const int p = atomicAdd(&s_gt, 1);
      sel_idx[p] = myi;
      sel_val[p] = band_ov[t];
    }
  }
  __syncthreads();
  // now sel_* holds exactly Kdim entries

  // output 1: zero the row, scatter the kept values
  float* lat = out_lat + (size_t)r * Ldim;
  float4 z; z.x = 0.f; z.y = 0.f; z.z = 0.f; z.w = 0.f;
  float4* lp = (float4*)lat;
  #pragma unroll
  for (int j = 0; j < 16; ++j) lp[t + j * 256] = z;
  __syncthreads();
  if (t < Kdim) lat[sel_idx[t]] = sel_val[t];

  // output 2: sparse decode + denormalize
  float a0 = 0.f, a1 = 0.f, a2 = 0.f;
  for (int j = 0; j < Kdim; ++j) {
    const float v = sel_val[j];
    const float* wr = Wdec + (size_t)sel_idx[j] * Ddim;
    a0 += v * wr[t];
    a1 += v * wr[t + 256];
    a2 += v * wr[t + 512];
  }
  const float sd = std_arr[r], mv = mu_arr[r];
  float* rec = out_rec + (size_t)r * Ddim;
  rec[t]       = (a0 + pre_bias[t]) * sd + mv;
  rec[t + 256] = (a1 + pre_bias[t + 256]) * sd + mv;
  rec[t + 512] = (a2 + pre_bias[t + 512]) * sd + mv;
}

// ---------------------------------------------------------------- launch
extern "C" void kernel_launch(void* const* d_in, const int* in_sizes, int n_in,
                              void* d_out, int out_size, void* d_ws, size_t ws_size,
                              hipStream_t stream) {
  const float* x     = (const float*)d_in[0];
  const float* pre_b = (const float*)d_in[1];
  const float* lat_b = (const float*)d_in[2];
  const float* W_enc = (const float*)d_in[3];
  const float* W_dec = (const float*)d_in[4];

  float* out0 = (float*)d_out;                 // latents_pre_act [B,L]
  float* out1 = out0 + (size_t)Bdim * Ldim;    // latents         [B,L]
  float* out2 = out1 + (size_t)Bdim * Ldim;    // recons          [B,D]

  char* p = (char*)d_ws;
  __hip_bfloat16* xh = (__hip_bfloat16*)p; p += (size_t)Bdim * Ddim * 2;
  __hip_bfloat16* xl = (__hip_bfloat16*)p; p += (size_t)Bdim * Ddim * 2;
  __hip_bfloat16* Wh = (__hip_bfloat16*)p; p += (size_t)Ldim * Ddim * 2;
  __hip_bfloat16* Wl = (__hip_bfloat16*)p; p += (size_t)Ldim * Ddim * 2;
  float* xn32 = (float*)p;                 p += (size_t)Bdim * Ddim * 4;
  float* Wt32 = (float*)p;                 p += (size_t)Ldim * Ddim * 4;
  float* muv  = (float*)p;                 p += (size_t)Bdim * 4;
  float* sdv  = (float*)p;

  normalize_kernel<<<Bdim, 256, 0, stream>>>(x, pre_b, xh, xl, xn32, muv, sdv);
  wsplit_kernel<<<dim3(Ldim / 32, Ddim / 32), 256, 0, stream>>>(W_enc, Wh, Wl, Wt32);
  encode_gemm_kernel<<<dim3(Ldim / 256, Bdim / 256), 512, 0, stream>>>(
      xh, xl, Wh, Wl, lat_b, out0);
  topk_decode_kernel<<<Bdim, 256, 0, stream>>>(
      out0, xn32, Wt32, lat_b, W_dec, pre_b, muv, sdv, out1, out2);
}